// Round 2
// baseline (172.322 us; speedup 1.0000x reference)
//
#include <hip/hip_runtime.h>
#include <hip/hip_bf16.h>

#define G_ 8
#define GIN_ 256
#define GOUT_ 256
#define NROWS_ 8192
#define LDX_ 2048   // = G_*GIN_ = row stride of x and out

typedef __attribute__((ext_vector_type(4))) float f32x4;
typedef __attribute__((ext_vector_type(8))) short bf16x8;

// ---------------------------------------------------------------------------
// Prep: W [G][GIN][GOUT] f32  ->  Wt [G][GOUT][GIN] bf16 (transposed+converted)
// Grid: 128 blocks x 256 threads. LDS-tiled transpose: coalesced both ways.
// ---------------------------------------------------------------------------
__global__ __launch_bounds__(256) void wprep_kernel(const float* __restrict__ W,
                                                    __hip_bfloat16* __restrict__ Wt) {
    __shared__ float tile[64][65];   // +1 pad: conflict-free transposed read
    const int bid = blockIdx.x;
    const int g  = bid >> 4;
    const int ot = (bid >> 2) & 3;   // o-tile (64 wide)
    const int it = bid & 3;          // i-tile (64 wide)
    const float* Wg = W + g * GIN_ * GOUT_;
    __hip_bfloat16* Wtg = Wt + g * GIN_ * GOUT_;
    const int lane_o = threadIdx.x & 63;
    const int sub    = threadIdx.x >> 6;   // 0..3
#pragma unroll
    for (int r = 0; r < 16; ++r) {
        int i = r * 4 + sub;
        tile[i][lane_o] = Wg[(it * 64 + i) * GOUT_ + ot * 64 + lane_o];
    }
    __syncthreads();
#pragma unroll
    for (int r = 0; r < 16; ++r) {
        int o = r * 4 + sub;
        Wtg[(ot * 64 + o) * GIN_ + it * 64 + lane_o] = __float2bfloat16(tile[lane_o][o]);
    }
}

// ---------------------------------------------------------------------------
// Main fused kernel — ZERO LDS, ZERO BARRIERS.
// Each wave: 32(M) x 64(N) output tile, B (64 cols x 256 K bf16) fully
// register-resident (128 VGPRs), A fragments loaded straight from global as
// f32 and converted in-register. K-loop fully unrolled, double-buffered A.
// Block = 4 waves stacked in M -> block tile 128(M) x 64(N).
// Grid: (8192/128) * (2048/64) = 64 * 32 = 2048 blocks.
// blockIdx m-major: consecutive blocks share the same x rows -> L2 reuse.
// ---------------------------------------------------------------------------
__global__ __launch_bounds__(256, 2) void gkan_kernel(const float* __restrict__ x,
                                                      const __hip_bfloat16* __restrict__ Wt,
                                                      const float* __restrict__ bias,
                                                      const float* __restrict__ pc,
                                                      const float* __restrict__ qc,
                                                      float* __restrict__ out) {
    const int bid   = blockIdx.x;
    const int mtile = bid >> 5;          // 0..63 : 128-row tiles
    const int ntile = bid & 31;          // 0..31 : 64-col tiles (8 groups x 4)
    const int g     = ntile >> 2;
    const int n0    = (ntile & 3) * 64;  // col offset within group

    const int t    = threadIdx.x;
    const int wave = t >> 6;
    const int lane = t & 63;
    const int lm   = lane & 15;
    const int quad = lane >> 4;

    const int m0 = mtile * 128 + wave * 32;   // wave's 32-row stripe

    // ---- B: register-resident fragments, loaded once ----
    bf16x8 Bfr[8][4];                    // [k-chunk][n-tile]
    {
        const __hip_bfloat16* Wg = Wt + (size_t)g * (GIN_ * GOUT_);
#pragma unroll
        for (int nt = 0; nt < 4; ++nt) {
            const __hip_bfloat16* Wn = Wg + (size_t)(n0 + nt * 16 + lm) * GIN_ + quad * 8;
#pragma unroll
            for (int kk = 0; kk < 8; ++kk)
                Bfr[kk][nt] = *(const bf16x8*)(Wn + kk * 32);
        }
    }

    const float* xr0 = x + (size_t)(m0 + lm) * LDX_ + g * GIN_ + quad * 8;
    const float* xr1 = xr0 + (size_t)16 * LDX_;

    f32x4 acc[2][4] = {};

    // ---- K-loop: fully unrolled, A double-buffered, no sync anywhere ----
    f32x4 ra[2][2][2];                   // [buf][m-tile][half]
    ra[0][0][0] = *(const f32x4*)(xr0);
    ra[0][0][1] = *(const f32x4*)(xr0 + 4);
    ra[0][1][0] = *(const f32x4*)(xr1);
    ra[0][1][1] = *(const f32x4*)(xr1 + 4);

#pragma unroll
    for (int kk = 0; kk < 8; ++kk) {
        const int cur = kk & 1, nxt = cur ^ 1;
        if (kk < 7) {
            const int ko = (kk + 1) * 32;
            ra[nxt][0][0] = *(const f32x4*)(xr0 + ko);
            ra[nxt][0][1] = *(const f32x4*)(xr0 + ko + 4);
            ra[nxt][1][0] = *(const f32x4*)(xr1 + ko);
            ra[nxt][1][1] = *(const f32x4*)(xr1 + ko + 4);
        }
        bf16x8 af[2];
#pragma unroll
        for (int mt = 0; mt < 2; ++mt) {
            const f32x4 a0 = ra[cur][mt][0], a1 = ra[cur][mt][1];
            union { __hip_bfloat16 h[8]; bf16x8 v; } cv;
            cv.h[0] = __float2bfloat16(a0.x);
            cv.h[1] = __float2bfloat16(a0.y);
            cv.h[2] = __float2bfloat16(a0.z);
            cv.h[3] = __float2bfloat16(a0.w);
            cv.h[4] = __float2bfloat16(a1.x);
            cv.h[5] = __float2bfloat16(a1.y);
            cv.h[6] = __float2bfloat16(a1.z);
            cv.h[7] = __float2bfloat16(a1.w);
            af[mt] = cv.v;
        }
#pragma unroll
        for (int mt = 0; mt < 2; ++mt)
#pragma unroll
            for (int nt = 0; nt < 4; ++nt)
                acc[mt][nt] = __builtin_amdgcn_mfma_f32_16x16x32_bf16(
                    af[mt], Bfr[kk][nt], acc[mt][nt], 0, 0, 0);
    }

    // ---- epilogue: bias + rational, coalesced dword stores ----
    const float p0 = pc[g * 4 + 0], p1 = pc[g * 4 + 1];
    const float p2 = pc[g * 4 + 2], p3 = pc[g * 4 + 3];
    const float q0 = qc[g * 3 + 0], q1 = qc[g * 3 + 1], q2 = qc[g * 3 + 2];

#pragma unroll
    for (int nt = 0; nt < 4; ++nt) {
        const int col = n0 + nt * 16 + lm;               // within group
        const float bb = bias[g * GOUT_ + col];
#pragma unroll
        for (int mt = 0; mt < 2; ++mt) {
#pragma unroll
            for (int r = 0; r < 4; ++r) {
                const int row = m0 + mt * 16 + quad * 4 + r;
                const float y   = acc[mt][nt][r] + bb;
                const float num = p0 + y * (p1 + y * (p2 + y * p3));
                const float den = 1.0f + fabsf(y * (q0 + y * (q1 + y * q2)));
                out[(size_t)row * LDX_ + g * GOUT_ + col] = num * __builtin_amdgcn_rcpf(den);
            }
        }
    }
}

extern "C" void kernel_launch(void* const* d_in, const int* in_sizes, int n_in,
                              void* d_out, int out_size, void* d_ws, size_t ws_size,
                              hipStream_t stream) {
    const float* x = (const float*)d_in[0];
    const float* W = (const float*)d_in[1];
    const float* b = (const float*)d_in[2];
    const float* p = (const float*)d_in[3];
    const float* q = (const float*)d_in[4];
    float* out = (float*)d_out;

    __hip_bfloat16* Wt = (__hip_bfloat16*)d_ws;   // 1 MiB bf16 transposed W

    wprep_kernel<<<128, 256, 0, stream>>>(W, Wt);
    gkan_kernel<<<2048, 256, 0, stream>>>(x, Wt, b, p, q, out);
}

// Round 3
// 154.073 us; speedup vs baseline: 1.1184x; 1.1184x over previous
//
#include <hip/hip_runtime.h>
#include <hip/hip_bf16.h>

#define G_ 8
#define GIN_ 256
#define GOUT_ 256
#define NROWS_ 8192
#define LDX_ 2048   // = G_*GIN_ = row stride of x and out

typedef __attribute__((ext_vector_type(4))) float f32x4;
typedef __attribute__((ext_vector_type(8))) short bf16x8;

// ---------------------------------------------------------------------------
// Prep: W [G][GIN][GOUT] f32  ->  Wt [G][GOUT][GIN] bf16 (transposed+converted)
// Grid: 128 blocks x 256 threads. LDS-tiled transpose: coalesced both ways.
// ---------------------------------------------------------------------------
__global__ __launch_bounds__(256) void wprep_kernel(const float* __restrict__ W,
                                                    __hip_bfloat16* __restrict__ Wt) {
    __shared__ float tile[64][65];   // +1 pad: conflict-free transposed read
    const int bid = blockIdx.x;
    const int g  = bid >> 4;
    const int ot = (bid >> 2) & 3;   // o-tile (64 wide)
    const int it = bid & 3;          // i-tile (64 wide)
    const float* Wg = W + g * GIN_ * GOUT_;
    __hip_bfloat16* Wtg = Wt + g * GIN_ * GOUT_;
    const int lane_o = threadIdx.x & 63;
    const int sub    = threadIdx.x >> 6;   // 0..3
#pragma unroll
    for (int r = 0; r < 16; ++r) {
        int i = r * 4 + sub;
        tile[i][lane_o] = Wg[(it * 64 + i) * GOUT_ + ot * 64 + lane_o];
    }
    __syncthreads();
#pragma unroll
    for (int r = 0; r < 16; ++r) {
        int o = r * 4 + sub;
        Wtg[(ot * 64 + o) * GIN_ + it * 64 + lane_o] = __float2bfloat16(tile[lane_o][o]);
    }
}

// ---------------------------------------------------------------------------
// Main fused kernel.
//  - B (128 cols x 256 K, bf16) staged into 64 KB LDS ONCE, XOR-swizzled in
//    16B units so ds_read_b128 fragment reads are conflict-free. One barrier.
//  - K-loop (8 chunks of 32, fully unrolled): A loaded global->reg as f32
//    (double-buffered), converted to bf16 in-register, B via ds_read_b128.
//    NO barriers in the loop -> waves free-run, loads pipeline on vmcnt.
//  - Block tile 128M x 128N (one group's half-width), 4 waves in 2x2,
//    each wave 64x64 via 4x4 grid of mfma_f32_16x16x32_bf16.
// Grid: 64 mtiles * 16 = 1024 blocks. bid = mtile*16 + nt*8 + g so the two
// blocks sharing an x-slice (nt=0,1) are 8 apart -> same XCD -> L2 reuse.
// ---------------------------------------------------------------------------
__global__ __launch_bounds__(256, 2) void gkan_kernel(const float* __restrict__ x,
                                                      const __hip_bfloat16* __restrict__ Wt,
                                                      const float* __restrict__ bias,
                                                      const float* __restrict__ pc,
                                                      const float* __restrict__ qc,
                                                      float* __restrict__ out) {
    __shared__ __align__(16) __hip_bfloat16 Bs[128 * 256];   // 64 KB

    const int bid   = blockIdx.x;
    const int mtile = bid >> 4;          // 0..63
    const int j     = bid & 15;
    const int ntile = j >> 3;            // 0..1  (128-col half of the group)
    const int g     = j & 7;
    const int n0    = ntile * 128;

    const int t    = threadIdx.x;
    const int wave = t >> 6;
    const int lane = t & 63;
    const int lm   = lane & 15;
    const int quad = lane >> 4;
    const int wrow = wave >> 1;          // m-half (0,1)
    const int wcol = wave & 1;           // n-half (0,1)

    // ---- stage B into LDS (once), XOR-swizzled 16B units ----
    {
        const __hip_bfloat16* Wg = Wt + (size_t)g * (GIN_ * GOUT_) + (size_t)n0 * GIN_;
#pragma unroll
        for (int i = 0; i < 16; ++i) {
            const int gidx = i * 256 + t;        // 0..4095 16B-units
            const int n = gidx >> 5;             // 0..127 (col)
            const int u = gidx & 31;             // 16B unit within 512B row
            const bf16x8 v = *(const bf16x8*)(Wg + n * GIN_ + u * 8);
            *(bf16x8*)(Bs + n * 256 + ((u ^ (n & 7)) << 3)) = v;
        }
    }
    __syncthreads();   // the only barrier

    // ---- K-loop: A global->reg (dbuf) + B from LDS, no barriers ----
    const float* xbase = x + (size_t)(mtile * 128 + wrow * 64 + lm) * LDX_
                           + g * GIN_ + quad * 8;

    f32x4 ra[2][4][2];                   // [buf][m-tile][half]
#pragma unroll
    for (int mt = 0; mt < 4; ++mt) {
        ra[0][mt][0] = *(const f32x4*)(xbase + (size_t)mt * 16 * LDX_);
        ra[0][mt][1] = *(const f32x4*)(xbase + (size_t)mt * 16 * LDX_ + 4);
    }

    f32x4 acc[4][4] = {};

#pragma unroll
    for (int kk = 0; kk < 8; ++kk) {
        const int cur = kk & 1, nxt = cur ^ 1;
        if (kk < 7) {
            const int ko = (kk + 1) * 32;
#pragma unroll
            for (int mt = 0; mt < 4; ++mt) {
                ra[nxt][mt][0] = *(const f32x4*)(xbase + (size_t)mt * 16 * LDX_ + ko);
                ra[nxt][mt][1] = *(const f32x4*)(xbase + (size_t)mt * 16 * LDX_ + ko + 4);
            }
        }

        bf16x8 bfr[4];
#pragma unroll
        for (int nt = 0; nt < 4; ++nt) {
            const int nloc = wcol * 64 + nt * 16 + lm;
            bfr[nt] = *(const bf16x8*)(Bs + nloc * 256 + (((kk * 4 + quad) ^ (nloc & 7)) << 3));
        }

        bf16x8 af[4];
#pragma unroll
        for (int mt = 0; mt < 4; ++mt) {
            const f32x4 a0 = ra[cur][mt][0], a1 = ra[cur][mt][1];
            union { __hip_bfloat16 h[8]; bf16x8 v; } cv;
            cv.h[0] = __float2bfloat16(a0.x);
            cv.h[1] = __float2bfloat16(a0.y);
            cv.h[2] = __float2bfloat16(a0.z);
            cv.h[3] = __float2bfloat16(a0.w);
            cv.h[4] = __float2bfloat16(a1.x);
            cv.h[5] = __float2bfloat16(a1.y);
            cv.h[6] = __float2bfloat16(a1.z);
            cv.h[7] = __float2bfloat16(a1.w);
            af[mt] = cv.v;
        }

#pragma unroll
        for (int mt = 0; mt < 4; ++mt)
#pragma unroll
            for (int nt = 0; nt < 4; ++nt)
                acc[mt][nt] = __builtin_amdgcn_mfma_f32_16x16x32_bf16(
                    af[mt], bfr[nt], acc[mt][nt], 0, 0, 0);
    }

    // ---- epilogue: bias + rational, coalesced dword stores ----
    const float p0 = pc[g * 4 + 0], p1 = pc[g * 4 + 1];
    const float p2 = pc[g * 4 + 2], p3 = pc[g * 4 + 3];
    const float q0 = qc[g * 3 + 0], q1 = qc[g * 3 + 1], q2 = qc[g * 3 + 2];

    const int m0w = mtile * 128 + wrow * 64;
#pragma unroll
    for (int nt = 0; nt < 4; ++nt) {
        const int col = n0 + wcol * 64 + nt * 16 + lm;    // within group
        const float bb = bias[g * GOUT_ + col];
#pragma unroll
        for (int mt = 0; mt < 4; ++mt) {
#pragma unroll
            for (int r = 0; r < 4; ++r) {
                const int row = m0w + mt * 16 + quad * 4 + r;
                const float y   = acc[mt][nt][r] + bb;
                const float num = p0 + y * (p1 + y * (p2 + y * p3));
                const float den = 1.0f + fabsf(y * (q0 + y * (q1 + y * q2)));
                out[(size_t)row * LDX_ + g * GOUT_ + col] = num * __builtin_amdgcn_rcpf(den);
            }
        }
    }
}

extern "C" void kernel_launch(void* const* d_in, const int* in_sizes, int n_in,
                              void* d_out, int out_size, void* d_ws, size_t ws_size,
                              hipStream_t stream) {
    const float* x = (const float*)d_in[0];
    const float* W = (const float*)d_in[1];
    const float* b = (const float*)d_in[2];
    const float* p = (const float*)d_in[3];
    const float* q = (const float*)d_in[4];
    float* out = (float*)d_out;

    __hip_bfloat16* Wt = (__hip_bfloat16*)d_ws;   // 1 MiB bf16 transposed W

    wprep_kernel<<<128, 256, 0, stream>>>(W, Wt);
    gkan_kernel<<<1024, 256, 0, stream>>>(x, Wt, b, p, q, out);
}

// Round 4
// 147.561 us; speedup vs baseline: 1.1678x; 1.0441x over previous
//
#include <hip/hip_runtime.h>
#include <hip/hip_bf16.h>

#define G_ 8
#define GIN_ 256
#define GOUT_ 256
#define NROWS_ 8192
#define LDX_ 2048   // = G_*GIN_ = row stride of x and out

typedef __attribute__((ext_vector_type(4))) float f32x4;
typedef __attribute__((ext_vector_type(8))) short bf16x8;

// ---------------------------------------------------------------------------
// Prep: W [G][GIN][GOUT] f32  ->  Wt [G][GOUT][GIN] bf16 (transposed+converted)
// Grid: 128 blocks x 256 threads. LDS-tiled transpose: coalesced both ways.
// ---------------------------------------------------------------------------
__global__ __launch_bounds__(256) void wprep_kernel(const float* __restrict__ W,
                                                    __hip_bfloat16* __restrict__ Wt) {
    __shared__ float tile[64][65];   // +1 pad: conflict-free transposed read
    const int bid = blockIdx.x;
    const int g  = bid >> 4;
    const int ot = (bid >> 2) & 3;   // o-tile (64 wide)
    const int it = bid & 3;          // i-tile (64 wide)
    const float* Wg = W + g * GIN_ * GOUT_;
    __hip_bfloat16* Wtg = Wt + g * GIN_ * GOUT_;
    const int lane_o = threadIdx.x & 63;
    const int sub    = threadIdx.x >> 6;   // 0..3
#pragma unroll
    for (int r = 0; r < 16; ++r) {
        int i = r * 4 + sub;
        tile[i][lane_o] = Wg[(it * 64 + i) * GOUT_ + ot * 64 + lane_o];
    }
    __syncthreads();
#pragma unroll
    for (int r = 0; r < 16; ++r) {
        int o = r * 4 + sub;
        Wtg[(ot * 64 + o) * GIN_ + it * 64 + lane_o] = __float2bfloat16(tile[lane_o][o]);
    }
}

// ---------------------------------------------------------------------------
// Main fused kernel.
//  Block tile: 128M x 64N of one group. 4 waves stacked in M (32M x 64N each,
//  acc = 2x4 MFMA tiles = 32 VGPRs). B strip (64 cols x 256 K bf16 = 32 KB)
//  staged to LDS once (XOR-swizzled 16B units -> 2-way reads = free), then a
//  barrier-free fully-unrolled K-loop: A loaded global->reg f32 with an
//  explicit DEPTH-2 prefetch (3 small buffers, 16 VGPRs each), converted to
//  bf16 in-register, B via ds_read_b128.
//  Low register pressure (~130 VGPR) is deliberate: it lets the allocator
//  KEEP the prefetch distance instead of collapsing it (R2/R3 failure mode).
// Grid: 64 mtiles * 32 strips = 2048 blocks; bid = mtile*32 + nt*8 + g so the
// 4 strips sharing an x-slice are 8 apart -> same XCD -> L2-local x reuse.
// ---------------------------------------------------------------------------
__global__ __launch_bounds__(256) void gkan_kernel(const float* __restrict__ x,
                                                   const __hip_bfloat16* __restrict__ Wt,
                                                   const float* __restrict__ bias,
                                                   const float* __restrict__ pc,
                                                   const float* __restrict__ qc,
                                                   float* __restrict__ out) {
    __shared__ __align__(16) __hip_bfloat16 Bs[64 * 256];   // 32 KB

    const int bid   = blockIdx.x;
    const int mtile = bid >> 5;          // 0..63
    const int j     = bid & 31;
    const int nt4   = j >> 3;            // 0..3 : 64-col strip within group
    const int g     = j & 7;
    const int n0    = nt4 * 64;

    const int t    = threadIdx.x;
    const int wave = t >> 6;
    const int lane = t & 63;
    const int lm   = lane & 15;
    const int quad = lane >> 4;

    // ---- stage B strip into LDS (once), XOR-swizzled in 16B units ----
    {
        const __hip_bfloat16* Wg = Wt + (size_t)g * (GIN_ * GOUT_) + (size_t)n0 * GIN_;
#pragma unroll
        for (int i = 0; i < 8; ++i) {
            const int v   = i * 256 + t;     // 0..2047 16B-units
            const int col = v >> 5;          // 0..63
            const int u   = v & 31;          // 16B unit within 512B k-row
            const bf16x8 val = *(const bf16x8*)(Wg + col * GIN_ + u * 8);
            const int usw = u ^ ((col & 7) << 2);
            *(bf16x8*)(Bs + col * GIN_ + usw * 8) = val;
        }
    }
    __syncthreads();   // the only barrier

    // ---- K-loop: A global->reg, explicit depth-2 prefetch, no barriers ----
    const float* xbase = x + (size_t)(mtile * 128 + wave * 32 + lm) * LDX_
                           + g * GIN_ + quad * 8;

    f32x4 abuf[3][2][2];   // [slot][m-tile][half] : 48 VGPRs total

#pragma unroll
    for (int s = 0; s < 2; ++s)
#pragma unroll
        for (int mt = 0; mt < 2; ++mt) {
            abuf[s][mt][0] = *(const f32x4*)(xbase + (size_t)mt * 16 * LDX_ + s * 32);
            abuf[s][mt][1] = *(const f32x4*)(xbase + (size_t)mt * 16 * LDX_ + s * 32 + 4);
        }

    f32x4 acc[2][4] = {};

#pragma unroll
    for (int kk = 0; kk < 8; ++kk) {
        const int slot = kk % 3;
        if (kk < 6) {
            const int ns = (kk + 2) % 3;
            const int ko = (kk + 2) * 32;
#pragma unroll
            for (int mt = 0; mt < 2; ++mt) {
                abuf[ns][mt][0] = *(const f32x4*)(xbase + (size_t)mt * 16 * LDX_ + ko);
                abuf[ns][mt][1] = *(const f32x4*)(xbase + (size_t)mt * 16 * LDX_ + ko + 4);
            }
        }

        // B fragments from LDS (swizzled; 2-way bank aliasing = free)
        bf16x8 bfr[4];
#pragma unroll
        for (int nt = 0; nt < 4; ++nt) {
            const int col = nt * 16 + lm;
            const int usw = (kk * 4 + quad) ^ ((col & 7) << 2);
            bfr[nt] = *(const bf16x8*)(Bs + col * GIN_ + usw * 8);
        }

        // convert this chunk's A to bf16
        bf16x8 af[2];
#pragma unroll
        for (int mt = 0; mt < 2; ++mt) {
            const f32x4 a0 = abuf[slot][mt][0], a1 = abuf[slot][mt][1];
            union { __hip_bfloat16 h[8]; bf16x8 v; } cv;
            cv.h[0] = __float2bfloat16(a0.x);
            cv.h[1] = __float2bfloat16(a0.y);
            cv.h[2] = __float2bfloat16(a0.z);
            cv.h[3] = __float2bfloat16(a0.w);
            cv.h[4] = __float2bfloat16(a1.x);
            cv.h[5] = __float2bfloat16(a1.y);
            cv.h[6] = __float2bfloat16(a1.z);
            cv.h[7] = __float2bfloat16(a1.w);
            af[mt] = cv.v;
        }

#pragma unroll
        for (int mt = 0; mt < 2; ++mt)
#pragma unroll
            for (int nt = 0; nt < 4; ++nt)
                acc[mt][nt] = __builtin_amdgcn_mfma_f32_16x16x32_bf16(
                    af[mt], bfr[nt], acc[mt][nt], 0, 0, 0);
    }

    // ---- epilogue: bias + rational, coalesced dword stores ----
    const float p0 = pc[g * 4 + 0], p1 = pc[g * 4 + 1];
    const float p2 = pc[g * 4 + 2], p3 = pc[g * 4 + 3];
    const float q0 = qc[g * 3 + 0], q1 = qc[g * 3 + 1], q2 = qc[g * 3 + 2];

    const int m0w = mtile * 128 + wave * 32;
#pragma unroll
    for (int nt = 0; nt < 4; ++nt) {
        const int col = n0 + nt * 16 + lm;               // within group
        const float bb = bias[g * GOUT_ + col];
#pragma unroll
        for (int mt = 0; mt < 2; ++mt) {
#pragma unroll
            for (int r = 0; r < 4; ++r) {
                const int row = m0w + mt * 16 + quad * 4 + r;
                const float y   = acc[mt][nt][r] + bb;
                const float num = p0 + y * (p1 + y * (p2 + y * p3));
                const float den = 1.0f + fabsf(y * (q0 + y * (q1 + y * q2)));
                out[(size_t)row * LDX_ + g * GOUT_ + col] = num * __builtin_amdgcn_rcpf(den);
            }
        }
    }
}

extern "C" void kernel_launch(void* const* d_in, const int* in_sizes, int n_in,
                              void* d_out, int out_size, void* d_ws, size_t ws_size,
                              hipStream_t stream) {
    const float* x = (const float*)d_in[0];
    const float* W = (const float*)d_in[1];
    const float* b = (const float*)d_in[2];
    const float* p = (const float*)d_in[3];
    const float* q = (const float*)d_in[4];
    float* out = (float*)d_out;

    __hip_bfloat16* Wt = (__hip_bfloat16*)d_ws;   // 1 MiB bf16 transposed W

    wprep_kernel<<<128, 256, 0, stream>>>(W, Wt);
    gkan_kernel<<<2048, 256, 0, stream>>>(x, Wt, b, p, q, out);
}